// Round 4
// baseline (133.110 us; speedup 1.0000x reference)
//
#include <hip/hip_runtime.h>

// Problem constants (fixed by the reference module)
#define B_ 16
#define L_ 2048
#define D_ 128
#define GROUP_ 16
#define NG_ (L_ / GROUP_)   // 128
#define LOG2E_ 1.44269504088896340736f

typedef float v2 __attribute__((ext_vector_type(2)));

// DPP mov (for butterfly stages within 16-lane rows)
template<int CTRL>
__device__ __forceinline__ float dpp_mov(float v) {
    return __int_as_float(
        __builtin_amdgcn_update_dpp(0, __float_as_int(v), CTRL, 0xF, 0xF, false));
}

// R13 = R12 structure with the xj-clobber bug fixed.
// Structure: ONE WAVE per (b,g) group. Lane l owns dims {2l, 2l+1} of all
// 16 rows. xj (row j's state for my dims) is my own xi[j] register ->
// zero LDS, zero barriers; the only cross-lane op is a 6-stage butterfly
// all-reduce of the 16 row-sims (DPP x4 + ds_swizzle xor16 + ds_bpermute
// xor32). 2048 groups = 2048 independent waves = 8 waves/CU.
//
// R12 bug: the pickup `if (r == jn) xj = xi[r]` lived inside the update
// loop that also READS xj -> rows r > j+1 used row j+1's state instead of
// row j's (absmax 16.8). Fix: capture into xj_next, commit after the loop.
__global__ __launch_bounds__(64, 2) void ncn_kernel(
    const float* __restrict__ x,       // (B, L, D)
    const int*   __restrict__ gt,      // (B, L) permutation
    const int*   __restrict__ ctxlens, // (B,)
    const float* __restrict__ W,       // (2D,)
    const float* __restrict__ nalpha,  // (2,)
    const float* __restrict__ ngamma,  // (2D,)
    const float* __restrict__ nbeta,   // (2D,)
    float* __restrict__ out)           // (2, B, L, D) concat: yi_out, ya_out
{
    const int blk  = blockIdx.x;
    const int b    = blk >> 7;          // / NG_
    const int g    = blk & (NG_ - 1);
    const int lane = threadIdx.x;       // 0..63
    const int d0   = lane << 1;         // 2 dims per lane

    const float a1 = nalpha[0];
    const float a2 = nalpha[1];
    const float ca = -a1 * LOG2E_;        // u = ca*(xi + sim*xj); ALPHA=0.5 folded
    const float S  = -2.0f * a2 * LOG2E_; // za = S*xa, so exp2(za) direct
    const bool  selMin = (S < 0.0f);      // leaky-relu under sign flip

    // Per-lane constants: just 12 floats.
    v2 Wiv, Wjv, G1S, B1S, G2v, B2v;
    {
        Wiv = *(const v2*)(W + d0);
        Wjv = *(const v2*)(W + D_ + d0);
        v2 g1 = *(const v2*)(ngamma + d0);
        v2 g2 = *(const v2*)(ngamma + D_ + d0);
        v2 b1 = *(const v2*)(nbeta + d0);
        v2 b2 = *(const v2*)(nbeta + D_ + d0);
        G1S = (S * 2.0f) * g1;        // S*(2*g1)
        B1S = S * (b1 - g1);          // S*(b1-g1)
        G2v = 2.0f * g2;
        B2v = b2 - g2;
    }

    // Tokens for the 16 rows of this group (uniform -> scalar loads).
    const int* gtp = gt + b * L_ + g * GROUP_;
    int tok[GROUP_];
#pragma unroll
    for (int r = 0; r < GROUP_; ++r) tok[r] = gtp[r];

    // Gather: xi[r] = x[b, tok[r], d0..d0+1]
    v2 xi[GROUP_], za[GROUP_];
#pragma unroll
    for (int r = 0; r < GROUP_; ++r) {
        xi[r] = *(const v2*)(x + ((size_t)(b * L_ + tok[r])) * D_ + d0);
        za[r] = (v2){0.0f, 0.0f};
    }

    v2 xj = xi[0];                       // row 0 opens the recurrence
    const int xaddr = (lane ^ 32) << 2;  // bpermute byte-addr for xor-32

    const v2 cav  = (v2){ca, ca};
    const v2 onev = (v2){1.0f, 1.0f};
    const v2 leak = (v2){0.01f, 0.01f};

#pragma unroll 1
    for (int j = 0; j < GROUP_; ++j) {
        // ---- partial sims: p[r] = xi[r].Wi + xj.Wj (2-dim partial per lane)
        v2 pj = xj * Wjv;
        v2 p[GROUP_];
#pragma unroll
        for (int r = 0; r < GROUP_; ++r)
            p[r] = __builtin_elementwise_fma(xi[r], Wiv, pj);

        // combine the 2 in-lane dims, pack rows pairwise into 8 v2
        v2 q[8];
#pragma unroll
        for (int k = 0; k < 8; ++k)
            q[k] = (v2){p[2 * k].x + p[2 * k].y, p[2 * k + 1].x + p[2 * k + 1].y};

        // ---- 6-stage butterfly all-reduce across 64 lanes (sum of each q elem)
#pragma unroll
        for (int k = 0; k < 8; ++k) { v2 t = {dpp_mov<0xB1>(q[k].x),  dpp_mov<0xB1>(q[k].y)};  q[k] += t; }
#pragma unroll
        for (int k = 0; k < 8; ++k) { v2 t = {dpp_mov<0x4E>(q[k].x),  dpp_mov<0x4E>(q[k].y)};  q[k] += t; }
#pragma unroll
        for (int k = 0; k < 8; ++k) { v2 t = {dpp_mov<0x141>(q[k].x), dpp_mov<0x141>(q[k].y)}; q[k] += t; }
#pragma unroll
        for (int k = 0; k < 8; ++k) { v2 t = {dpp_mov<0x140>(q[k].x), dpp_mov<0x140>(q[k].y)}; q[k] += t; }
        // stage 5: xor-16 via ds_swizzle bit-mode (within 32-lane groups)
#pragma unroll
        for (int k = 0; k < 8; ++k) {
            v2 t;
            t.x = __int_as_float(__builtin_amdgcn_ds_swizzle(__float_as_int(q[k].x), 0x401F));
            t.y = __int_as_float(__builtin_amdgcn_ds_swizzle(__float_as_int(q[k].y), 0x401F));
            q[k] += t;
        }
        // stage 6: xor-32 via ds_bpermute (full 64-lane crossbar)
#pragma unroll
        for (int k = 0; k < 8; ++k) {
            v2 t;
            t.x = __int_as_float(__builtin_amdgcn_ds_bpermute(xaddr, __float_as_int(q[k].x)));
            t.y = __int_as_float(__builtin_amdgcn_ds_bpermute(xaddr, __float_as_int(q[k].y)));
            q[k] += t;
        }
        // q[k] = {sim[2k], sim[2k+1]} replicated in every lane.

        const int jn = j + 1;
        v2 xj_next = xj;   // committed AFTER the loop (R12 bug fix)

        // ---- elementwise update of all 16 rows (16 independent ILP chains)
#pragma unroll
        for (int r = 0; r < GROUP_; ++r) {
            const float s  = (r & 1) ? q[r >> 1].y : q[r >> 1].x;
            const v2 simv  = (v2){s, s};
            v2 T2 = __builtin_elementwise_fma(simv, xj, xi[r]);
            v2 u  = cav * T2;
            v2 e1 = (v2){__builtin_amdgcn_exp2f(u.x), __builtin_amdgcn_exp2f(u.y)};
            v2 d1 = e1 + onev;
            v2 r1 = (v2){__builtin_amdgcn_rcpf(d1.x), __builtin_amdgcn_rcpf(d1.y)}; // inf-safe
            v2 tnS = __builtin_elementwise_fma(G1S, r1, B1S);        // S*(g1*tanh+b1)
            v2 alt = tnS * leak;
            v2 FvS = selMin ? __builtin_elementwise_min(tnS, alt)
                            : __builtin_elementwise_max(tnS, alt);
            za[r] += FvS;                                            // za = S * xa
            v2 e2 = (v2){__builtin_amdgcn_exp2f(za[r].x), __builtin_amdgcn_exp2f(za[r].y)};
            v2 d2 = e2 + onev;
            v2 r2 = (v2){__builtin_amdgcn_rcpf(d2.x), __builtin_amdgcn_rcpf(d2.y)};
            xi[r] = __builtin_elementwise_fma(G2v, r2, xi[r] + B2v); // xi += g2*tanh+b2
            // capture next step's broadcaster (static r, uniform jn) -- do NOT
            // touch the live xj that later rows still read this step.
            if (r == jn) xj_next = xi[r];
        }
        xj = xj_next;
    }

    // Recover xa = za / S
    const float invS = 1.0f / S;
    const v2 invSv = (v2){invS, invS};

    const bool valid = (g * GROUP_) < ctxlens[b];

    float* o1 = out + d0;
    float* o2 = o1 + (size_t)B_ * L_ * D_;
#pragma unroll
    for (int r = 0; r < GROUP_; ++r) {
        v2 yi = xi[r];
        v2 ya = za[r] * invSv;
        if (!valid) { yi = (v2){0, 0}; ya = (v2){0, 0}; }
        const size_t off = ((size_t)(b * L_ + tok[r])) * D_;
        *(v2*)(o1 + off) = yi;
        *(v2*)(o2 + off) = ya;
    }
}

extern "C" void kernel_launch(void* const* d_in, const int* in_sizes, int n_in,
                              void* d_out, int out_size, void* d_ws, size_t ws_size,
                              hipStream_t stream) {
    const float* x  = (const float*)d_in[0];
    const int*   gt = (const int*)d_in[1];
    const int*   cl = (const int*)d_in[2];
    const float* W  = (const float*)d_in[3];
    const float* na = (const float*)d_in[4];
    const float* ng = (const float*)d_in[5];
    const float* nb = (const float*)d_in[6];
    float* out = (float*)d_out;

    ncn_kernel<<<B_ * NG_, 64, 0, stream>>>(x, gt, cl, W, na, ng, nb, out);
}

// Round 5
// 111.896 us; speedup vs baseline: 1.1896x; 1.1896x over previous
//
#include <hip/hip_runtime.h>

// Problem constants (fixed by the reference module)
#define B_ 16
#define L_ 2048
#define D_ 128
#define GROUP_ 16
#define NG_ (L_ / GROUP_)   // 128
#define LOG2E_ 1.44269504088896340736f

typedef float v2 __attribute__((ext_vector_type(2)));

// DPP-based butterfly add within each 16-lane row (full-rate VALU, no LDS).
template<int CTRL>
__device__ __forceinline__ float dpp_add(float v) {
    int x = __builtin_amdgcn_update_dpp(0, __float_as_int(v), CTRL, 0xF, 0xF, false);
    return v + __int_as_float(x);
}
__device__ __forceinline__ float row16_sum(float v) {
    v = dpp_add<0xB1>(v);   // quad_perm(1,0,3,2)  ~ xor 1
    v = dpp_add<0x4E>(v);   // quad_perm(2,3,0,1)  ~ xor 2
    v = dpp_add<0x141>(v);  // row_half_mirror     ~ xor 4
    v = dpp_add<0x140>(v);  // row_mirror          ~ xor 8
    return v;
}

// R14: R9 structure (best measured: 45us) + issue-count reduction.
// Evidence R9-R13: wall tracks full-rate VALU issue ~1:1 (R11 added VALU
// ops -> proportional slowdown; trans swaps bought nothing). So: cut VALU
// ops/elem. (a) scaled state cxi = ca*xi kills the per-elem ca*T2 mul
// (weights pre-scaled 1/ca, output unscaled once at the end); (b) the
// leaky-relu select is split into two uniform-branch loop copies so each
// elem pays ONE v_pk_min/max (the ?: inside unrolled code risks
// min+max+cndmask); (c) e+1 folded into the rcp operand, splats dropped.
// Per-elem: ~11-13 VALU + 4 trans -> 9 VALU + 4 trans.
//
// Per step j: all rows read row j's cxj from LDS (double-buffered), row
// j+1 publishes its updated cxi into the other buffer; ONE barrier orders
// both visibility and WAR reuse (R9-proven).
//
// STEP_LOOP macro: SELFN = min (S<0) or max (S>=0), uniform per launch.
#define STEP_LOOP(SELFN)                                                      \
    for (int j = 0; j < GROUP_; ++j) {                                        \
        const int p = j & 1;                                                  \
        v2 xjv[4];                                                            \
        {                                                                     \
            float4 tA = *(const float4*)&s_xj[p][d0];                         \
            float4 tB = *(const float4*)&s_xj[p][d0 + 4];                     \
            xjv[0] = (v2){tA.x, tA.y}; xjv[1] = (v2){tA.z, tA.w};             \
            xjv[2] = (v2){tB.x, tB.y}; xjv[3] = (v2){tB.z, tB.w};             \
        }                                                                     \
        v2 sv = (v2){0.0f, 0.0f};                                             \
        _Pragma("unroll")                                                     \
        for (int k = 0; k < 4; ++k) sv = __builtin_elementwise_fma(cxi[k], Wi[k], sv); \
        _Pragma("unroll")                                                     \
        for (int k = 0; k < 4; ++k) sv = __builtin_elementwise_fma(xjv[k], Wj[k], sv); \
        const float sim = row16_sum(sv.x + sv.y);                             \
        const v2 simv = (v2){sim, sim};                                       \
        _Pragma("unroll")                                                     \
        for (int k = 0; k < 4; ++k) {                                         \
            v2 u  = __builtin_elementwise_fma(simv, xjv[k], cxi[k]);          \
            v2 r1 = (v2){__builtin_amdgcn_rcpf(__builtin_amdgcn_exp2f(u.x) + 1.0f),   \
                         __builtin_amdgcn_rcpf(__builtin_amdgcn_exp2f(u.y) + 1.0f)};  \
            v2 tnS = __builtin_elementwise_fma(G1S[k], r1, B1S[k]);           \
            v2 FvS = SELFN(tnS, tnS * leak);                                  \
            za[k] += FvS;                                                     \
            v2 r2 = (v2){__builtin_amdgcn_rcpf(__builtin_amdgcn_exp2f(za[k].x) + 1.0f), \
                         __builtin_amdgcn_rcpf(__builtin_amdgcn_exp2f(za[k].y) + 1.0f)}; \
            cxi[k] = __builtin_elementwise_fma(G2c[k], r2, cxi[k] + B2c[k]);  \
        }                                                                     \
        if (j + 1 < GROUP_ && row == j + 1) {                                 \
            *(v2*)&s_xj[p ^ 1][d0]     = cxi[0];                              \
            *(v2*)&s_xj[p ^ 1][d0 + 2] = cxi[1];                              \
            *(v2*)&s_xj[p ^ 1][d0 + 4] = cxi[2];                              \
            *(v2*)&s_xj[p ^ 1][d0 + 6] = cxi[3];                              \
        }                                                                     \
        __syncthreads();                                                      \
    }

__global__ __launch_bounds__(256, 4) void ncn_kernel(
    const float* __restrict__ x,       // (B, L, D)
    const int*   __restrict__ gt,      // (B, L) permutation
    const int*   __restrict__ ctxlens, // (B,)
    const float* __restrict__ W,       // (2D,)
    const float* __restrict__ nalpha,  // (2,)
    const float* __restrict__ ngamma,  // (2D,)
    const float* __restrict__ nbeta,   // (2D,)
    float* __restrict__ out)           // (2, B, L, D) concat: yi_out, ya_out
{
    const int blk = blockIdx.x;
    const int b   = blk >> 7;      // / NG_
    const int g   = blk & (NG_ - 1);
    const int tid = threadIdx.x;
    const int row = tid >> 4;      // 0..15 (token within group)
    const int rl  = tid & 15;      // 0..15 (lane within row)
    const int d0  = rl << 3;       // 8 d-elements per thread

    __shared__ float s_xj[2][D_];  // double-buffered broadcast row (holds cxj)

    const float a1 = nalpha[0];
    const float a2 = nalpha[1];
    const float ca = -a1 * LOG2E_;        // u = ca*(xi + sim*xj); ALPHA=0.5 folded
    const float S  = -2.0f * a2 * LOG2E_; // za = S*xa, so exp2(za) direct
    const float inv_ca = 1.0f / ca;       // (a1 != 0 on this problem's inputs)
    const bool  selMin = (S < 0.0f);      // leaky-relu under sign flip

    // Per-chunk constants in registers (reused 16x), as packed v2 pairs.
    // Wi,Wj pre-scaled by 1/ca so sim = dot(cxi,Wi') + dot(cxj,Wj').
    // G2c,B2c pre-scaled by ca so cxi' = fma(G2c, r2, cxi + B2c).
    v2 Wi[4], Wj[4], G1S[4], B1S[4], G2c[4], B2c[4];
    {
        float4 wA = *(const float4*)(W + d0);
        float4 wB = *(const float4*)(W + d0 + 4);
        float4 vA = *(const float4*)(W + D_ + d0);
        float4 vB = *(const float4*)(W + D_ + d0 + 4);
        Wi[0] = inv_ca * (v2){wA.x, wA.y}; Wi[1] = inv_ca * (v2){wA.z, wA.w};
        Wi[2] = inv_ca * (v2){wB.x, wB.y}; Wi[3] = inv_ca * (v2){wB.z, wB.w};
        Wj[0] = inv_ca * (v2){vA.x, vA.y}; Wj[1] = inv_ca * (v2){vA.z, vA.w};
        Wj[2] = inv_ca * (v2){vB.x, vB.y}; Wj[3] = inv_ca * (v2){vB.z, vB.w};

        float4 g1A = *(const float4*)(ngamma + d0);
        float4 g1B = *(const float4*)(ngamma + d0 + 4);
        float4 g2A = *(const float4*)(ngamma + D_ + d0);
        float4 g2B = *(const float4*)(ngamma + D_ + d0 + 4);
        float4 b1A = *(const float4*)(nbeta + d0);
        float4 b1B = *(const float4*)(nbeta + d0 + 4);
        float4 b2A = *(const float4*)(nbeta + D_ + d0);
        float4 b2B = *(const float4*)(nbeta + D_ + d0 + 4);

        v2 g1v[4] = {(v2){g1A.x,g1A.y},(v2){g1A.z,g1A.w},(v2){g1B.x,g1B.y},(v2){g1B.z,g1B.w}};
        v2 b1v[4] = {(v2){b1A.x,b1A.y},(v2){b1A.z,b1A.w},(v2){b1B.x,b1B.y},(v2){b1B.z,b1B.w}};
        v2 g2v[4] = {(v2){g2A.x,g2A.y},(v2){g2A.z,g2A.w},(v2){g2B.x,g2B.y},(v2){g2B.z,g2B.w}};
        v2 b2v[4] = {(v2){b2A.x,b2A.y},(v2){b2A.z,b2A.w},(v2){b2B.x,b2B.y},(v2){b2B.z,b2B.w}};
#pragma unroll
        for (int k = 0; k < 4; ++k) {
            G1S[k] = (S * 2.0f) * g1v[k];        // S*(2*g1)
            B1S[k] = S * (b1v[k] - g1v[k]);      // S*(b1-g1)
            G2c[k] = (ca * 2.0f) * g2v[k];       // ca*(2*g2)
            B2c[k] = ca * (b2v[k] - g2v[k]);     // ca*(b2-g2)
        }
    }

    // Gather this row's token; state is cxi = ca * xi.
    const int l   = g * GROUP_ + row;
    const int tok = gt[b * L_ + l];
    const float* xp = x + ((size_t)(b * L_ + tok)) * D_ + d0;

    v2 cxi[4], za[4];
    {
        float4 xA = *(const float4*)xp;
        float4 xB = *(const float4*)(xp + 4);
        const v2 cav = (v2){ca, ca};
        cxi[0] = cav * (v2){xA.x, xA.y}; cxi[1] = cav * (v2){xA.z, xA.w};
        cxi[2] = cav * (v2){xB.x, xB.y}; cxi[3] = cav * (v2){xB.z, xB.w};
    }
#pragma unroll
    for (int k = 0; k < 4; ++k) za[k] = (v2){0.0f, 0.0f};

    // Row 0 publishes its initial cxi into buffer 0
    if (row == 0) {
        *(v2*)&s_xj[0][d0]     = cxi[0];
        *(v2*)&s_xj[0][d0 + 2] = cxi[1];
        *(v2*)&s_xj[0][d0 + 4] = cxi[2];
        *(v2*)&s_xj[0][d0 + 6] = cxi[3];
    }
    __syncthreads();

    const v2 leak = (v2){0.01f, 0.01f};

    // Uniform split: each path pays exactly one v_pk_min / v_pk_max per elem.
    if (selMin) {
        STEP_LOOP(__builtin_elementwise_min)
    } else {
        STEP_LOOP(__builtin_elementwise_max)
    }

    // Recover xi = cxi / ca and xa = za / S.
    const float invS = 1.0f / S;
    const v2 invSv  = (v2){invS, invS};
    const v2 invCav = (v2){inv_ca, inv_ca};
    v2 xi[4], xa[4];
#pragma unroll
    for (int k = 0; k < 4; ++k) {
        xi[k] = cxi[k] * invCav;
        xa[k] = za[k] * invSv;
    }

    const bool valid = (g * GROUP_) < ctxlens[b];
    if (!valid) {
#pragma unroll
        for (int k = 0; k < 4; ++k) { xi[k] = (v2){0,0}; xa[k] = (v2){0,0}; }
    }

    // Scatter back through the permutation (bijective -> every out elem written)
    float* o1 = out + ((size_t)(b * L_ + tok)) * D_ + d0;
    float* o2 = o1 + (size_t)B_ * L_ * D_;
    float4 s1A = {xi[0].x, xi[0].y, xi[1].x, xi[1].y};
    float4 s1B = {xi[2].x, xi[2].y, xi[3].x, xi[3].y};
    float4 s2A = {xa[0].x, xa[0].y, xa[1].x, xa[1].y};
    float4 s2B = {xa[2].x, xa[2].y, xa[3].x, xa[3].y};
    *(float4*)o1       = s1A;
    *(float4*)(o1 + 4) = s1B;
    *(float4*)o2       = s2A;
    *(float4*)(o2 + 4) = s2B;
}

extern "C" void kernel_launch(void* const* d_in, const int* in_sizes, int n_in,
                              void* d_out, int out_size, void* d_ws, size_t ws_size,
                              hipStream_t stream) {
    const float* x  = (const float*)d_in[0];
    const int*   gt = (const int*)d_in[1];
    const int*   cl = (const int*)d_in[2];
    const float* W  = (const float*)d_in[3];
    const float* na = (const float*)d_in[4];
    const float* ng = (const float*)d_in[5];
    const float* nb = (const float*)d_in[6];
    float* out = (float*)d_out;

    ncn_kernel<<<B_ * NG_, 256, 0, stream>>>(x, gt, cl, W, na, ng, nb, out);
}